// Round 1
// 844.253 us; speedup vs baseline: 1.1128x; 1.1128x over previous
//
#include <hip/hip_runtime.h>
#include <hip/hip_bf16.h>
#include <stdint.h>

#define S 2048
#define D 64
#define H 4096
#define NB 8

typedef __bf16 bf16;
typedef __attribute__((ext_vector_type(8))) __bf16 bf16x8;
typedef __attribute__((ext_vector_type(4))) __bf16 bf16x4;
typedef __attribute__((ext_vector_type(4))) float f32x4;

// Raw LDS-DMA, invisible to the compiler's waitcnt pass (no auto vmcnt(0)).
// M0 = wave-uniform LDS byte offset; HW adds lane*16B. (R5-verified.)
__device__ __forceinline__ void dma16_raw(const bf16* g, uint32_t m0_bytes) {
  uint32_t m0s = __builtin_amdgcn_readfirstlane(m0_bytes);
  asm volatile("s_mov_b32 m0, %1\n\t"
               "global_load_lds_dwordx4 %0, off"
               :: "v"(g), "s"(m0s) : "memory");
}

__device__ __forceinline__ uint32_t lds_off_bytes(const void* p) {
  return (uint32_t)(uintptr_t)(__attribute__((address_space(3))) const void*)p;
}

// ---------------------------------------------------------------------------
// Transpose + cast: W [K][N] f32  ->  Wt [N][K] bf16   (weights, once per call)
// ---------------------------------------------------------------------------
__global__ __launch_bounds__(256) void transpose_cast(const float* __restrict__ W,
                                                      bf16* __restrict__ Wt,
                                                      int K, int N) {
  __shared__ float tile[64][65];
  int k0 = blockIdx.y * 64, n0 = blockIdx.x * 64;
  int c = threadIdx.x & 63;
  int r4 = threadIdx.x >> 6;
#pragma unroll
  for (int i = 0; i < 16; ++i) {
    int r = i * 4 + r4;
    tile[r][c] = W[(size_t)(k0 + r) * N + n0 + c];
  }
  __syncthreads();
#pragma unroll
  for (int i = 0; i < 16; ++i) {
    int r = i * 4 + r4;
    Wt[(size_t)(n0 + r) * K + k0 + c] = (bf16)tile[c][r];
  }
}

// ---------------------------------------------------------------------------
// Elementwise cast f32 -> bf16 (for Q, K). One float4 per thread.
// ---------------------------------------------------------------------------
__global__ __launch_bounds__(256) void cast_bf16(const float* __restrict__ x,
                                                 bf16* __restrict__ y) {
  int i = blockIdx.x * 256 + threadIdx.x;
  f32x4 v = ((const f32x4*)x)[i];
  bf16x4 o;
  o[0] = (bf16)v.x; o[1] = (bf16)v.y; o[2] = (bf16)v.z; o[3] = (bf16)v.w;
  ((bf16x4*)y)[i] = o;
}

// ---------------------------------------------------------------------------
// gemm_bt: kept (verified) for QK^T only (K=64 -> no deep pipeline to fill).
// 128x256 tile, BK=32, 4 waves, 2-barrier raw-DMA pipeline, swizzled LDS.
// ---------------------------------------------------------------------------
template <int RELU, int OUTBF16>
__global__ __launch_bounds__(256, 2) void gemm_bt(const bf16* __restrict__ A,
                                                  const bf16* __restrict__ Bt,
                                                  const float* __restrict__ bias,
                                                  void* __restrict__ Cv,
                                                  float scale,
                                                  int M, int N, int K,
                                                  long strideA, long strideB,
                                                  long strideC) {
  __shared__ __align__(16) bf16 smem[24576];
  int tid = threadIdx.x;
  int lane = tid & 63;
  int w = tid >> 6;

  int m0 = blockIdx.y * 128, n0 = blockIdx.x * 256;
  const bf16* Ab = A + (size_t)blockIdx.z * strideA;
  const bf16* Btb = Bt + (size_t)blockIdx.z * strideB;

  int grow = tid >> 2;
  int gcol = (((lane & 3) ^ ((lane >> 3) & 3)) * 8);
  const bf16* gA0 = Ab + (size_t)(m0 + grow) * K + gcol;
  const bf16* gA1 = gA0 + (size_t)64 * K;
  const bf16* gB0 = Btb + (size_t)(n0 + grow) * K + gcol;
  const bf16* gB1 = gB0 + (size_t)64 * K;
  const bf16* gB2 = gB0 + (size_t)128 * K;
  const bf16* gB3 = gB0 + (size_t)192 * K;

  uint32_t ldsBase = lds_off_bytes(&smem[0]);
  uint32_t wb = (uint32_t)(w * 1024);
  uint32_t mA[2], mB[2];
  mA[0] = ldsBase + wb;          mA[1] = ldsBase + 8192 + wb;
  mB[0] = ldsBase + 16384 + wb;  mB[1] = ldsBase + 32768 + wb;

  int mw = (w & 1) * 64, nw = (w >> 1) * 128;
  int lr = lane & 15;
  int ck = lane >> 4;
  int swz = (ck ^ ((lr >> 1) & 3)) * 8;
  const bf16* paBase = smem + (size_t)(mw + lr) * 32 + swz;
  const bf16* pbBase = smem + 8192 + (size_t)(nw + lr) * 32 + swz;

  f32x4 zero = {0.f, 0.f, 0.f, 0.f};
  f32x4 acc[4][8];
#pragma unroll
  for (int mt = 0; mt < 4; ++mt)
#pragma unroll
    for (int nt = 0; nt < 8; ++nt) acc[mt][nt] = zero;

  const int niter = K / 32;

#define STAGE(buf, koff)                                 \
  do {                                                   \
    dma16_raw(gA0 + (koff), mA[buf]);                    \
    dma16_raw(gA1 + (koff), mA[buf] + 4096);             \
    dma16_raw(gB0 + (koff), mB[buf]);                    \
    dma16_raw(gB1 + (koff), mB[buf] + 4096);             \
    dma16_raw(gB2 + (koff), mB[buf] + 8192);             \
    dma16_raw(gB3 + (koff), mB[buf] + 12288);            \
  } while (0)

  STAGE(0, 0);
  STAGE(1, 32);

  for (int it = 0; it < niter; ++it) {
    int buf = it & 1;
    asm volatile("s_waitcnt vmcnt(6)\n\ts_barrier" ::: "memory");
    const bf16* pa = paBase + buf * 4096;
    const bf16* pb = pbBase + buf * 8192;
    bf16x8 af[4], bfr[8];
#pragma unroll
    for (int mt = 0; mt < 4; ++mt) af[mt] = *(const bf16x8*)(pa + mt * (16 * 32));
#pragma unroll
    for (int nt = 0; nt < 8; ++nt) bfr[nt] = *(const bf16x8*)(pb + nt * (16 * 32));
    asm volatile("s_waitcnt lgkmcnt(0)\n\ts_barrier" ::: "memory");
    int kpre = it + 2 < niter ? (it + 2) * 32 : (niter - 1) * 32;
    STAGE(buf, kpre);
#pragma unroll
    for (int mt = 0; mt < 4; ++mt)
#pragma unroll
      for (int nt = 0; nt < 8; ++nt)
        acc[mt][nt] = __builtin_amdgcn_mfma_f32_16x16x32_bf16(af[mt], bfr[nt],
                                                              acc[mt][nt], 0, 0, 0);
  }
#undef STAGE
  asm volatile("s_waitcnt vmcnt(0)" ::: "memory");

  int mbase = m0 + mw + (lane >> 4) * 4;
  int nbase = n0 + nw + (lane & 15);
#pragma unroll
  for (int mt = 0; mt < 4; ++mt) {
#pragma unroll
    for (int nt = 0; nt < 8; ++nt) {
      int n = nbase + nt * 16;
      float bv = bias ? bias[n] : 0.f;
#pragma unroll
      for (int reg = 0; reg < 4; ++reg) {
        int m = mbase + mt * 16 + reg;
        float v = acc[mt][nt][reg] * scale + bv;
        if (RELU) v = fmaxf(v, 0.f);
        if (OUTBF16) {
          bf16* C = (bf16*)Cv + (size_t)blockIdx.z * strideC;
          C[(size_t)m * N + n] = (bf16)v;
        } else {
          float* C = (float*)Cv + (size_t)blockIdx.z * strideC;
          C[(size_t)m * N + n] = v;
        }
      }
    }
  }
}

// ---------------------------------------------------------------------------
// gemm256: 256x256 tile, BK=64, 512 threads (8 waves as 2Mx4N, 128x64/wave),
// 128 KiB LDS, 8-phase (4 phases/K-tile) counted-vmcnt schedule (T2+T3+T4+T5).
// R8: the 2-barrier gemm_bt structure ceilings at ~930 TF (MfmaUtil 42%);
// this is the m201-template port targeting ~1500 TF.
//
// LDS regions (bytes): A [0,65536) = [parity][half(128 rows)][row][64 k] bf16;
//                      B [65536,131072) same shape over Bt rows (C cols).
// Swizzle: 16B granule g at row r holds global granule g^(r&7) (read-side XOR,
// write-side pre-swizzled GLOBAL source; LDS dest stays linear -- rule #21).
//
// Quadrant order per K-tile (gray): (Aq0,Bq0)(Aq0,Bq1)(Aq1,Bq1)(Aq1,Bq0).
// Wave (wm,wn): Aq rows = q*128 + wm*64 + [0,64); Bq cols = q*128 + wn*32 + [0,32)
// => each quad touches exactly one 128-row LDS half => half slots have 2-phase
// read windows, allowing mid-tile overwrite of the CURRENT parity:
//   ph0: stage A h1 (tile+1, parity^1)   ph1: stage B h0 (tile+1, parity^1)
//   ph2: stage A h0 (tile+2, parity!)    ph3: stage B h1 (tile+2, parity!)
// vmcnt(4) ONCE per K-tile (end of ph3): the 2 allowed-outstanding halves are
// always the ph2/ph3 (tile+2) stages; all 4 halves of the next tile provably
// landed (each half issued >= 4 stage-slots before its covering wait).
// Never vmcnt(0) in the loop. Barriers are raw s_barrier (no waitcnt drain);
// ds_reads are compiler loads so hipcc inserts the lgkmcnt before MFMA use.
// Regs: 128 acc + 32 af + 32 bf0/bf1 + ~20 misc < 256 cap from (512,2).
// Requires K%64==0, K>=128, M%256==0, N%256==0.
// ---------------------------------------------------------------------------
template <int RELU, int OUTBF16>
__global__ __launch_bounds__(512, 2) void gemm256(const bf16* __restrict__ A,
                                                  const bf16* __restrict__ Bt,
                                                  const float* __restrict__ bias,
                                                  void* __restrict__ Cv,
                                                  float scale,
                                                  int M, int N, int K,
                                                  long strideA, long strideB,
                                                  long strideC) {
  __shared__ __align__(16) bf16 smem[65536];  // 128 KiB
  const char* smc = (const char*)&smem[0];

  int tid = threadIdx.x;
  int lane = tid & 63;
  int w = tid >> 6;
  int wm = w >> 2, wn = w & 3;  // 2M x 4N wave grid

  // bijective XCD swizzle (m204) over the x-y plane; z = batch untouched.
  unsigned gx = gridDim.x;
  unsigned nwg = gx * gridDim.y;
  unsigned flat = blockIdx.y * gx + blockIdx.x;
  unsigned q = nwg >> 3, r = nwg & 7, xcd = flat & 7, idx = flat >> 3;
  unsigned wg = (xcd < r ? xcd * (q + 1) : r * (q + 1) + (xcd - r) * q) + idx;
  int n0 = (int)(wg % gx) * 256;
  int m0 = (int)(wg / gx) * 256;

  const bf16* Ab = A + (size_t)blockIdx.z * strideA;
  const bf16* Btb = Bt + (size_t)blockIdx.z * strideB;

  // Staging: thread t covers LDS byte 16*t of each 8 KiB (64-row) load chunk:
  // row = t>>3, granule = t&7. Pre-swizzled global granule = (t&7)^(row&7).
  int trow = tid >> 3;
  int tg = (tid & 7) ^ (trow & 7);
  const bf16* pgA = Ab + (size_t)(m0 + trow) * K + tg * 8;
  const bf16* pgB = Btb + (size_t)(n0 + trow) * K + tg * 8;
  const size_t s64K = (size_t)K * 64;

  uint32_t ldsBase = lds_off_bytes(&smem[0]);
  uint32_t mb = ldsBase + (uint32_t)(w * 1024);  // wave-uniform DMA base

  // LDS read bases. A-frag (16x16x32): row=lane&15, k=(lane>>4)*8.
  // byte = rowInHalf*128 + (((kk*4+j) ^ (lane&7)))*16
  //      = (lane&15)*128 + ((j^(lane&3))*16) + ((kk^b2)*64) + subtile imms.
  int j = lane >> 4, b2 = (lane >> 2) & 1;
  uint32_t rbA0 = (uint32_t)(wm * 8192 + (lane & 15) * 128 +
                             ((j ^ (lane & 3)) * 16) + b2 * 64);
  uint32_t rbA1 = rbA0 ^ 64u;  // kk=1 flips the granule's k-bit (byte bit 6)
  uint32_t rbB0 = (uint32_t)(65536 + wn * 4096 + (lane & 15) * 128 +
                             ((j ^ (lane & 3)) * 16) + b2 * 64);
  uint32_t rbB1 = rbB0 ^ 64u;

  f32x4 acc[8][4];  // [qa*4+mt][qb*2+nt]
#pragma unroll
  for (int a = 0; a < 8; ++a)
#pragma unroll
    for (int b = 0; b < 4; ++b) acc[a][b] = (f32x4){0.f, 0.f, 0.f, 0.f};

  bf16x8 af[4][2];   // current A quad [mt][kk]
  bf16x8 bf0[2][2];  // B quad 0 (held ph0 -> ph3, no re-read)
  bf16x8 bf1[2][2];  // B quad 1

#define STG_A(PI, HH, LL, KC) \
  dma16_raw(pgA + (size_t)(2 * (HH) + (LL)) * s64K + (KC), \
            mb + (PI) * 32768 + (HH) * 16384 + (LL) * 8192)
#define STG_B(PI, HH, LL, KC) \
  dma16_raw(pgB + (size_t)(2 * (HH) + (LL)) * s64K + (KC), \
            mb + 65536 + (PI) * 32768 + (HH) * 16384 + (LL) * 8192)
#define STAGE_AH(PI, HH, KC) do { STG_A(PI, HH, 0, KC); STG_A(PI, HH, 1, KC); } while (0)
#define STAGE_BH(PI, HH, KC) do { STG_B(PI, HH, 0, KC); STG_B(PI, HH, 1, KC); } while (0)

#define RDA(PI, QA)                                                            \
  do {                                                                        \
    _Pragma("unroll") for (int mt = 0; mt < 4; ++mt) {                        \
      af[mt][0] = *(const bf16x8*)(smc + rbA0 + ((PI) * 32768 + (QA) * 16384 + mt * 2048)); \
      af[mt][1] = *(const bf16x8*)(smc + rbA1 + ((PI) * 32768 + (QA) * 16384 + mt * 2048)); \
    }                                                                         \
  } while (0)
#define RDB(PI, QB, BF)                                                        \
  do {                                                                        \
    _Pragma("unroll") for (int nt = 0; nt < 2; ++nt) {                        \
      BF[nt][0] = *(const bf16x8*)(smc + rbB0 + ((PI) * 32768 + (QB) * 16384 + nt * 2048)); \
      BF[nt][1] = *(const bf16x8*)(smc + rbB1 + ((PI) * 32768 + (QB) * 16384 + nt * 2048)); \
    }                                                                         \
  } while (0)

#define MFMA_Q(QA, QB, BF)                                                     \
  do {                                                                        \
    __builtin_amdgcn_s_setprio(1);                                            \
    _Pragma("unroll") for (int mt = 0; mt < 4; ++mt)                          \
      _Pragma("unroll") for (int nt = 0; nt < 2; ++nt) {                      \
        f32x4 c = acc[(QA) * 4 + mt][(QB) * 2 + nt];                          \
        c = __builtin_amdgcn_mfma_f32_16x16x32_bf16(af[mt][0], BF[nt][0], c, 0, 0, 0); \
        c = __builtin_amdgcn_mfma_f32_16x16x32_bf16(af[mt][1], BF[nt][1], c, 0, 0, 0); \
        acc[(QA) * 4 + mt][(QB) * 2 + nt] = c;                                \
      }                                                                       \
    __builtin_amdgcn_s_setprio(0);                                            \
  } while (0)

#define BAR() asm volatile("s_barrier" ::: "memory")
#define VMC4() asm volatile("s_waitcnt vmcnt(4)" ::: "memory")

  // One K-tile = 4 phases. KC1 = k-offset (elems) of tile+1, KC2 = tile+2.
#define TILE(PI, KC1, KC2)            \
  do {                                \
    RDA(PI, 0);                       \
    RDB(PI, 0, bf0);                  \
    STAGE_AH((PI) ^ 1, 1, KC1);       \
    BAR();                            \
    MFMA_Q(0, 0, bf0);                \
    BAR();                            \
    RDB(PI, 1, bf1);                  \
    STAGE_BH((PI) ^ 1, 0, KC1);       \
    BAR();                            \
    MFMA_Q(0, 1, bf1);                \
    BAR();                            \
    RDA(PI, 1);                       \
    STAGE_AH(PI, 0, KC2);             \
    BAR();                            \
    MFMA_Q(1, 1, bf1);                \
    BAR();                            \
    STAGE_BH(PI, 1, KC2);             \
    BAR();                            \
    MFMA_Q(1, 0, bf0);                \
    VMC4();                           \
    BAR();                            \
  } while (0)

  // Prologue: issue halves in steady-state order so vmcnt(4) leaves exactly
  // the two tile-1 (ph2/ph3-slot) halves outstanding:
  //   Ah0(0) Bh1(0) Ah1(0) Bh0(0) | Ah0(1) Bh1(1)
  STAGE_AH(0, 0, 0);
  STAGE_BH(0, 1, 0);
  STAGE_AH(0, 1, 0);
  STAGE_BH(0, 0, 0);
  STAGE_AH(1, 0, 64);
  STAGE_BH(1, 1, 64);
  asm volatile("s_waitcnt vmcnt(4)\n\ts_barrier" ::: "memory");

  const int NT = K / 64;  // even (K = 2048 or 4096)
  for (int T = 0; T < NT; T += 2) {
    int c1 = (T + 1) * 64;
    int c2 = (T + 2 < NT ? T + 2 : NT - 1) * 64;  // tail: clamp DATA only;
    int c3 = (T + 3 < NT ? T + 3 : NT - 1) * 64;  // dest slots are never read
    TILE(0, c1, c2);
    TILE(1, c2, c3);
  }
#undef TILE
#undef VMC4
#undef BAR
#undef MFMA_Q
#undef RDB
#undef RDA
#undef STAGE_BH
#undef STAGE_AH
#undef STG_B
#undef STG_A

  // drain leftover DMAs before LDS is reused by the next block
  asm volatile("s_waitcnt vmcnt(0)" ::: "memory");

  // epilogue; C/D layout per frag: col = lane&15, row = (lane>>4)*4 + reg
  int rowb = m0 + wm * 64 + ((lane >> 4) << 2);
  int colb = n0 + wn * 32 + (lane & 15);
#pragma unroll
  for (int fn = 0; fn < 4; ++fn) {
    int n = colb + (fn >> 1) * 128 + (fn & 1) * 16;
    float bv = bias ? bias[n] : 0.f;
#pragma unroll
    for (int fm = 0; fm < 8; ++fm) {
      int mrow = rowb + (fm >> 2) * 128 + (fm & 3) * 16;
#pragma unroll
      for (int reg = 0; reg < 4; ++reg) {
        float v = acc[fm][fn][reg] * scale + bv;
        if (RELU) v = fmaxf(v, 0.f);
        int m = mrow + reg;
        if (OUTBF16) {
          bf16* C = (bf16*)Cv + (size_t)blockIdx.z * strideC;
          C[(size_t)m * N + n] = (bf16)v;
        } else {
          float* C = (float*)Cv + (size_t)blockIdx.z * strideC;
          C[(size_t)m * N + n] = v;
        }
      }
    }
  }
}

// ---------------------------------------------------------------------------
// Fused softmax (over k) + attn @ V.  4 q-rows per block, 256 threads.
// ---------------------------------------------------------------------------
__global__ __launch_bounds__(256) void softmax_av(const float* __restrict__ adj,
                                                  const float* __restrict__ V,
                                                  float* __restrict__ out,
                                                  long adjStride) {
  int z = blockIdx.y;
  const float* adjb = adj + (size_t)z * adjStride;
  const float* Vb = V + (size_t)z * (S * D);
  float* outb = out + (size_t)z * (S * D);
  int q0 = blockIdx.x * 4;
  __shared__ __align__(16) float attnL[4][S];
  __shared__ float red[4][4][64];
  __shared__ float rsum[4];
  int tid = threadIdx.x;
  int w = tid >> 6, lane = tid & 63;

  const float* rowp = adjb + (size_t)(q0 + w) * S;
  float lm = -1e30f;
  f32x4 rv[8];
#pragma unroll
  for (int k = 0; k < 8; ++k) {
    rv[k] = *(const f32x4*)&rowp[lane * 4 + k * 256];
    lm = fmaxf(fmaxf(fmaxf(rv[k].x, rv[k].y), fmaxf(rv[k].z, rv[k].w)), lm);
  }
#pragma unroll
  for (int off = 32; off > 0; off >>= 1) lm = fmaxf(lm, __shfl_xor(lm, off));
  float s = 0.f;
#pragma unroll
  for (int k = 0; k < 8; ++k) {
    f32x4 e;
    e.x = __expf(rv[k].x - lm);
    e.y = __expf(rv[k].y - lm);
    e.z = __expf(rv[k].z - lm);
    e.w = __expf(rv[k].w - lm);
    *(f32x4*)&attnL[w][lane * 4 + k * 256] = e;
    s += e.x + e.y + e.z + e.w;
  }
#pragma unroll
  for (int off = 32; off > 0; off >>= 1) s += __shfl_xor(s, off);
  if (lane == 0) rsum[w] = s;
  __syncthreads();

  float acc0 = 0.f, acc1 = 0.f, acc2 = 0.f, acc3 = 0.f;
  int kbase = w * 512;
  for (int kk = 0; kk < 512; kk += 4) {
    int k = kbase + kk;
    float v0 = Vb[(size_t)(k + 0) * D + lane];
    float v1 = Vb[(size_t)(k + 1) * D + lane];
    float v2 = Vb[(size_t)(k + 2) * D + lane];
    float v3 = Vb[(size_t)(k + 3) * D + lane];
    f32x4 a0 = *(const f32x4*)&attnL[0][k];
    f32x4 a1 = *(const f32x4*)&attnL[1][k];
    f32x4 a2 = *(const f32x4*)&attnL[2][k];
    f32x4 a3 = *(const f32x4*)&attnL[3][k];
    acc0 += a0.x * v0 + a0.y * v1 + a0.z * v2 + a0.w * v3;
    acc1 += a1.x * v0 + a1.y * v1 + a1.z * v2 + a1.w * v3;
    acc2 += a2.x * v0 + a2.y * v1 + a2.z * v2 + a2.w * v3;
    acc3 += a3.x * v0 + a3.y * v1 + a3.z * v2 + a3.w * v3;
  }
  red[w][0][lane] = acc0;
  red[w][1][lane] = acc1;
  red[w][2][lane] = acc2;
  red[w][3][lane] = acc3;
  __syncthreads();
  int r = tid >> 6, d = tid & 63;
  float v = red[0][r][d] + red[1][r][d] + red[2][r][d] + red[3][r][d];
  outb[(size_t)(q0 + r) * D + d] = v / rsum[r];
}

// ---------------------------------------------------------------------------
extern "C" void kernel_launch(void* const* d_in, const int* in_sizes, int n_in,
                              void* d_out, int out_size, void* d_ws, size_t ws_size,
                              hipStream_t stream) {
  const float* Q  = (const float*)d_in[0];
  const float* Km = (const float*)d_in[1];
  const float* V  = (const float*)d_in[2];
  const float* W1 = (const float*)d_in[3];
  const float* b1 = (const float*)d_in[4];
  const float* W2 = (const float*)d_in[5];
  const float* b2 = (const float*)d_in[6];
  float* out = (float*)d_out;
  char* ws = (char*)d_ws;

  // layout: W1t 16M | W2t 16M | Qb16 2M | Kb16 2M | X (Sc bf16 / adj f32,
  // aliased) G*16M | h G*16M.  footprint = 36M + G*32M bytes.
  bf16* W1t  = (bf16*)ws;
  bf16* W2t  = (bf16*)(ws + 16777216);
  bf16* Qb16 = (bf16*)(ws + 33554432);
  bf16* Kb16 = (bf16*)(ws + 35651584);

  transpose_cast<<<dim3(H / 64, S / 64), 256, 0, stream>>>(W1, W1t, S, H);
  transpose_cast<<<dim3(S / 64, H / 64), 256, 0, stream>>>(W2, W2t, H, S);
  cast_bf16<<<dim3(NB * S * D / 1024), 256, 0, stream>>>(Q, Qb16);
  cast_bf16<<<dim3(NB * S * D / 1024), 256, 0, stream>>>(Km, Kb16);

  int G = 1;
  if (ws_size >= 306184192ULL) G = 8;        // 292 MiB (R7 ran G=8 OK)
  else if (ws_size >= 171966464ULL) G = 4;
  else if (ws_size >= 104857600ULL) G = 2;

  bf16* Sc   = (bf16*)(ws + 37748736);
  float* adj = (float*)(ws + 37748736);
  bf16* h    = (bf16*)(ws + 37748736 + (size_t)G * 16777216);

  for (int b0 = 0; b0 < NB; b0 += G) {
    // scores = (Q @ K^T) / 8 via MFMA (K-dim = 64: keep the verified gemm_bt)
    gemm_bt<0, 1><<<dim3(S / 256, S / 128, G), 256, 0, stream>>>(
        Qb16 + (size_t)b0 * S * D, Kb16 + (size_t)b0 * S * D, nullptr, Sc,
        0.125f, S, S, D, (long)S * D, (long)S * D, (long)S * S);
    // big MLP GEMMs on the 8-phase 256^2 schedule
    gemm256<1, 1><<<dim3(H / 256, S / 256, G), 512, 0, stream>>>(
        Sc, W1t, b1, h, 1.0f, S, H, S, (long)S * S, 0L, (long)S * H);
    gemm256<0, 0><<<dim3(S / 256, S / 256, G), 512, 0, stream>>>(
        h, W2t, b2, adj, 1.0f, S, S, H, (long)S * H, 0L, (long)S * S);
    softmax_av<<<dim3(S / 4, G), 256, 0, stream>>>(
        adj, V + (size_t)b0 * S * D, out + (size_t)b0 * S * D, (long)S * S);
  }
}

// Round 2
// 666.168 us; speedup vs baseline: 1.4102x; 1.2673x over previous
//
#include <hip/hip_runtime.h>
#include <hip/hip_bf16.h>
#include <stdint.h>

#define S 2048
#define D 64
#define H 4096
#define NB 8

typedef __bf16 bf16;
typedef __attribute__((ext_vector_type(8))) __bf16 bf16x8;
typedef __attribute__((ext_vector_type(4))) __bf16 bf16x4;
typedef __attribute__((ext_vector_type(4))) float f32x4;

// Raw LDS-DMA, invisible to the compiler's waitcnt pass (no auto vmcnt(0)).
// M0 = wave-uniform LDS byte offset; HW adds lane*16B. (R5-verified.)
__device__ __forceinline__ void dma16_raw(const bf16* g, uint32_t m0_bytes) {
  uint32_t m0s = __builtin_amdgcn_readfirstlane(m0_bytes);
  asm volatile("s_mov_b32 m0, %1\n\t"
               "global_load_lds_dwordx4 %0, off"
               :: "v"(g), "s"(m0s) : "memory");
}

__device__ __forceinline__ uint32_t lds_off_bytes(const void* p) {
  return (uint32_t)(uintptr_t)(__attribute__((address_space(3))) const void*)p;
}

// ---------------------------------------------------------------------------
// Transpose + cast: W [K][N] f32  ->  Wt [N][K] bf16   (weights, once per call)
// ---------------------------------------------------------------------------
__global__ __launch_bounds__(256) void transpose_cast(const float* __restrict__ W,
                                                      bf16* __restrict__ Wt,
                                                      int K, int N) {
  __shared__ float tile[64][65];
  int k0 = blockIdx.y * 64, n0 = blockIdx.x * 64;
  int c = threadIdx.x & 63;
  int r4 = threadIdx.x >> 6;
#pragma unroll
  for (int i = 0; i < 16; ++i) {
    int r = i * 4 + r4;
    tile[r][c] = W[(size_t)(k0 + r) * N + n0 + c];
  }
  __syncthreads();
#pragma unroll
  for (int i = 0; i < 16; ++i) {
    int r = i * 4 + r4;
    Wt[(size_t)(n0 + r) * K + k0 + c] = (bf16)tile[c][r];
  }
}

// ---------------------------------------------------------------------------
// Batched transpose + cast for V: V [z][S][D] f32 -> Vt [z][D][S] bf16.
// Runs per group iteration into the (dead) h workspace region. ~2 us.
// ---------------------------------------------------------------------------
__global__ __launch_bounds__(256) void vt_cast(const float* __restrict__ V,
                                               bf16* __restrict__ Vt) {
  __shared__ float tile[64][65];
  int z = blockIdx.y;
  int s0 = blockIdx.x * 64;
  const float* Vb = V + (size_t)z * (S * D);
  bf16* Vtb = Vt + (size_t)z * (D * S);
  int c = threadIdx.x & 63;
  int r4 = threadIdx.x >> 6;
#pragma unroll
  for (int i = 0; i < 16; ++i) {
    int r = i * 4 + r4;
    tile[r][c] = Vb[(size_t)(s0 + r) * D + c];
  }
  __syncthreads();
#pragma unroll
  for (int i = 0; i < 16; ++i) {
    int r = i * 4 + r4;  // r = d index
    Vtb[(size_t)r * S + s0 + c] = (bf16)tile[c][r];
  }
}

// ---------------------------------------------------------------------------
// Elementwise cast f32 -> bf16 (for Q, K). One float4 per thread.
// ---------------------------------------------------------------------------
__global__ __launch_bounds__(256) void cast_bf16(const float* __restrict__ x,
                                                 bf16* __restrict__ y) {
  int i = blockIdx.x * 256 + threadIdx.x;
  f32x4 v = ((const f32x4*)x)[i];
  bf16x4 o;
  o[0] = (bf16)v.x; o[1] = (bf16)v.y; o[2] = (bf16)v.z; o[3] = (bf16)v.w;
  ((bf16x4*)y)[i] = o;
}

// ---------------------------------------------------------------------------
// gemm_bt: kept (verified) for QK^T only (K=64 -> no deep pipeline to fill).
// 128x256 tile, BK=32, 4 waves, 2-barrier raw-DMA pipeline, swizzled LDS.
// ---------------------------------------------------------------------------
template <int RELU, int OUTBF16>
__global__ __launch_bounds__(256, 2) void gemm_bt(const bf16* __restrict__ A,
                                                  const bf16* __restrict__ Bt,
                                                  const float* __restrict__ bias,
                                                  void* __restrict__ Cv,
                                                  float scale,
                                                  int M, int N, int K,
                                                  long strideA, long strideB,
                                                  long strideC) {
  __shared__ __align__(16) bf16 smem[24576];
  int tid = threadIdx.x;
  int lane = tid & 63;
  int w = tid >> 6;

  int m0 = blockIdx.y * 128, n0 = blockIdx.x * 256;
  const bf16* Ab = A + (size_t)blockIdx.z * strideA;
  const bf16* Btb = Bt + (size_t)blockIdx.z * strideB;

  int grow = tid >> 2;
  int gcol = (((lane & 3) ^ ((lane >> 3) & 3)) * 8);
  const bf16* gA0 = Ab + (size_t)(m0 + grow) * K + gcol;
  const bf16* gA1 = gA0 + (size_t)64 * K;
  const bf16* gB0 = Btb + (size_t)(n0 + grow) * K + gcol;
  const bf16* gB1 = gB0 + (size_t)64 * K;
  const bf16* gB2 = gB0 + (size_t)128 * K;
  const bf16* gB3 = gB0 + (size_t)192 * K;

  uint32_t ldsBase = lds_off_bytes(&smem[0]);
  uint32_t wb = (uint32_t)(w * 1024);
  uint32_t mA[2], mB[2];
  mA[0] = ldsBase + wb;          mA[1] = ldsBase + 8192 + wb;
  mB[0] = ldsBase + 16384 + wb;  mB[1] = ldsBase + 32768 + wb;

  int mw = (w & 1) * 64, nw = (w >> 1) * 128;
  int lr = lane & 15;
  int ck = lane >> 4;
  int swz = (ck ^ ((lr >> 1) & 3)) * 8;
  const bf16* paBase = smem + (size_t)(mw + lr) * 32 + swz;
  const bf16* pbBase = smem + 8192 + (size_t)(nw + lr) * 32 + swz;

  f32x4 zero = {0.f, 0.f, 0.f, 0.f};
  f32x4 acc[4][8];
#pragma unroll
  for (int mt = 0; mt < 4; ++mt)
#pragma unroll
    for (int nt = 0; nt < 8; ++nt) acc[mt][nt] = zero;

  const int niter = K / 32;

#define STAGE(buf, koff)                                 \
  do {                                                   \
    dma16_raw(gA0 + (koff), mA[buf]);                    \
    dma16_raw(gA1 + (koff), mA[buf] + 4096);             \
    dma16_raw(gB0 + (koff), mB[buf]);                    \
    dma16_raw(gB1 + (koff), mB[buf] + 4096);             \
    dma16_raw(gB2 + (koff), mB[buf] + 8192);             \
    dma16_raw(gB3 + (koff), mB[buf] + 12288);            \
  } while (0)

  STAGE(0, 0);
  STAGE(1, 32);

  for (int it = 0; it < niter; ++it) {
    int buf = it & 1;
    asm volatile("s_waitcnt vmcnt(6)\n\ts_barrier" ::: "memory");
    const bf16* pa = paBase + buf * 4096;
    const bf16* pb = pbBase + buf * 8192;
    bf16x8 af[4], bfr[8];
#pragma unroll
    for (int mt = 0; mt < 4; ++mt) af[mt] = *(const bf16x8*)(pa + mt * (16 * 32));
#pragma unroll
    for (int nt = 0; nt < 8; ++nt) bfr[nt] = *(const bf16x8*)(pb + nt * (16 * 32));
    asm volatile("s_waitcnt lgkmcnt(0)\n\ts_barrier" ::: "memory");
    int kpre = it + 2 < niter ? (it + 2) * 32 : (niter - 1) * 32;
    STAGE(buf, kpre);
#pragma unroll
    for (int mt = 0; mt < 4; ++mt)
#pragma unroll
      for (int nt = 0; nt < 8; ++nt)
        acc[mt][nt] = __builtin_amdgcn_mfma_f32_16x16x32_bf16(af[mt], bfr[nt],
                                                              acc[mt][nt], 0, 0, 0);
  }
#undef STAGE
  asm volatile("s_waitcnt vmcnt(0)" ::: "memory");

  int mbase = m0 + mw + (lane >> 4) * 4;
  int nbase = n0 + nw + (lane & 15);
#pragma unroll
  for (int mt = 0; mt < 4; ++mt) {
#pragma unroll
    for (int nt = 0; nt < 8; ++nt) {
      int n = nbase + nt * 16;
      float bv = bias ? bias[n] : 0.f;
#pragma unroll
      for (int reg = 0; reg < 4; ++reg) {
        int m = mbase + mt * 16 + reg;
        float v = acc[mt][nt][reg] * scale + bv;
        if (RELU) v = fmaxf(v, 0.f);
        if (OUTBF16) {
          bf16* C = (bf16*)Cv + (size_t)blockIdx.z * strideC;
          C[(size_t)m * N + n] = (bf16)v;
        } else {
          float* C = (float*)Cv + (size_t)blockIdx.z * strideC;
          C[(size_t)m * N + n] = v;
        }
      }
    }
  }
}

// ---------------------------------------------------------------------------
// gemm256: 256x256 tile, BK=64, 512 threads (8 waves as 2Mx4N, 128x64/wave),
// 128 KiB LDS, 8-phase (4 phases/K-tile) counted-vmcnt schedule (T2+T3+T4+T5).
// R8: took the MLP GEMMs from ~930 TF (MfmaUtil 42%) to >1200 TF.
// See R8 comment block for the full schedule derivation.
// ---------------------------------------------------------------------------
template <int RELU, int OUTBF16>
__global__ __launch_bounds__(512, 2) void gemm256(const bf16* __restrict__ A,
                                                  const bf16* __restrict__ Bt,
                                                  const float* __restrict__ bias,
                                                  void* __restrict__ Cv,
                                                  float scale,
                                                  int M, int N, int K,
                                                  long strideA, long strideB,
                                                  long strideC) {
  __shared__ __align__(16) bf16 smem[65536];  // 128 KiB
  const char* smc = (const char*)&smem[0];

  int tid = threadIdx.x;
  int lane = tid & 63;
  int w = tid >> 6;
  int wm = w >> 2, wn = w & 3;  // 2M x 4N wave grid

  // bijective XCD swizzle (m204) over the x-y plane; z = batch untouched.
  unsigned gx = gridDim.x;
  unsigned nwg = gx * gridDim.y;
  unsigned flat = blockIdx.y * gx + blockIdx.x;
  unsigned q = nwg >> 3, r = nwg & 7, xcd = flat & 7, idx = flat >> 3;
  unsigned wg = (xcd < r ? xcd * (q + 1) : r * (q + 1) + (xcd - r) * q) + idx;
  int n0 = (int)(wg % gx) * 256;
  int m0 = (int)(wg / gx) * 256;

  const bf16* Ab = A + (size_t)blockIdx.z * strideA;
  const bf16* Btb = Bt + (size_t)blockIdx.z * strideB;

  // Staging: thread t covers LDS byte 16*t of each 8 KiB (64-row) load chunk:
  // row = t>>3, granule = t&7. Pre-swizzled global granule = (t&7)^(row&7).
  int trow = tid >> 3;
  int tg = (tid & 7) ^ (trow & 7);
  const bf16* pgA = Ab + (size_t)(m0 + trow) * K + tg * 8;
  const bf16* pgB = Btb + (size_t)(n0 + trow) * K + tg * 8;
  const size_t s64K = (size_t)K * 64;

  uint32_t ldsBase = lds_off_bytes(&smem[0]);
  uint32_t mb = ldsBase + (uint32_t)(w * 1024);  // wave-uniform DMA base

  // LDS read bases. A-frag (16x16x32): row=lane&15, k=(lane>>4)*8.
  int j = lane >> 4, b2 = (lane >> 2) & 1;
  uint32_t rbA0 = (uint32_t)(wm * 8192 + (lane & 15) * 128 +
                             ((j ^ (lane & 3)) * 16) + b2 * 64);
  uint32_t rbA1 = rbA0 ^ 64u;
  uint32_t rbB0 = (uint32_t)(65536 + wn * 4096 + (lane & 15) * 128 +
                             ((j ^ (lane & 3)) * 16) + b2 * 64);
  uint32_t rbB1 = rbB0 ^ 64u;

  f32x4 acc[8][4];  // [qa*4+mt][qb*2+nt]
#pragma unroll
  for (int a = 0; a < 8; ++a)
#pragma unroll
    for (int b = 0; b < 4; ++b) acc[a][b] = (f32x4){0.f, 0.f, 0.f, 0.f};

  bf16x8 af[4][2];   // current A quad [mt][kk]
  bf16x8 bf0[2][2];  // B quad 0 (held ph0 -> ph3, no re-read)
  bf16x8 bf1[2][2];  // B quad 1

#define STG_A(PI, HH, LL, KC) \
  dma16_raw(pgA + (size_t)(2 * (HH) + (LL)) * s64K + (KC), \
            mb + (PI) * 32768 + (HH) * 16384 + (LL) * 8192)
#define STG_B(PI, HH, LL, KC) \
  dma16_raw(pgB + (size_t)(2 * (HH) + (LL)) * s64K + (KC), \
            mb + 65536 + (PI) * 32768 + (HH) * 16384 + (LL) * 8192)
#define STAGE_AH(PI, HH, KC) do { STG_A(PI, HH, 0, KC); STG_A(PI, HH, 1, KC); } while (0)
#define STAGE_BH(PI, HH, KC) do { STG_B(PI, HH, 0, KC); STG_B(PI, HH, 1, KC); } while (0)

#define RDA(PI, QA)                                                            \
  do {                                                                        \
    _Pragma("unroll") for (int mt = 0; mt < 4; ++mt) {                        \
      af[mt][0] = *(const bf16x8*)(smc + rbA0 + ((PI) * 32768 + (QA) * 16384 + mt * 2048)); \
      af[mt][1] = *(const bf16x8*)(smc + rbA1 + ((PI) * 32768 + (QA) * 16384 + mt * 2048)); \
    }                                                                         \
  } while (0)
#define RDB(PI, QB, BF)                                                        \
  do {                                                                        \
    _Pragma("unroll") for (int nt = 0; nt < 2; ++nt) {                        \
      BF[nt][0] = *(const bf16x8*)(smc + rbB0 + ((PI) * 32768 + (QB) * 16384 + nt * 2048)); \
      BF[nt][1] = *(const bf16x8*)(smc + rbB1 + ((PI) * 32768 + (QB) * 16384 + nt * 2048)); \
    }                                                                         \
  } while (0)

#define MFMA_Q(QA, QB, BF)                                                     \
  do {                                                                        \
    __builtin_amdgcn_s_setprio(1);                                            \
    _Pragma("unroll") for (int mt = 0; mt < 4; ++mt)                          \
      _Pragma("unroll") for (int nt = 0; nt < 2; ++nt) {                      \
        f32x4 c = acc[(QA) * 4 + mt][(QB) * 2 + nt];                          \
        c = __builtin_amdgcn_mfma_f32_16x16x32_bf16(af[mt][0], BF[nt][0], c, 0, 0, 0); \
        c = __builtin_amdgcn_mfma_f32_16x16x32_bf16(af[mt][1], BF[nt][1], c, 0, 0, 0); \
        acc[(QA) * 4 + mt][(QB) * 2 + nt] = c;                                \
      }                                                                       \
    __builtin_amdgcn_s_setprio(0);                                            \
  } while (0)

#define BAR() asm volatile("s_barrier" ::: "memory")
#define VMC4() asm volatile("s_waitcnt vmcnt(4)" ::: "memory")

#define TILE(PI, KC1, KC2)            \
  do {                                \
    RDA(PI, 0);                       \
    RDB(PI, 0, bf0);                  \
    STAGE_AH((PI) ^ 1, 1, KC1);       \
    BAR();                            \
    MFMA_Q(0, 0, bf0);                \
    BAR();                            \
    RDB(PI, 1, bf1);                  \
    STAGE_BH((PI) ^ 1, 0, KC1);       \
    BAR();                            \
    MFMA_Q(0, 1, bf1);                \
    BAR();                            \
    RDA(PI, 1);                       \
    STAGE_AH(PI, 0, KC2);             \
    BAR();                            \
    MFMA_Q(1, 1, bf1);                \
    BAR();                            \
    STAGE_BH(PI, 1, KC2);             \
    BAR();                            \
    MFMA_Q(1, 0, bf0);                \
    VMC4();                           \
    BAR();                            \
  } while (0)

  // Prologue: issue halves in steady-state order so vmcnt(4) leaves exactly
  // the two tile-1 (ph2/ph3-slot) halves outstanding.
  STAGE_AH(0, 0, 0);
  STAGE_BH(0, 1, 0);
  STAGE_AH(0, 1, 0);
  STAGE_BH(0, 0, 0);
  STAGE_AH(1, 0, 64);
  STAGE_BH(1, 1, 64);
  asm volatile("s_waitcnt vmcnt(4)\n\ts_barrier" ::: "memory");

  const int NT = K / 64;  // even (K = 2048 or 4096)
  for (int T = 0; T < NT; T += 2) {
    int c1 = (T + 1) * 64;
    int c2 = (T + 2 < NT ? T + 2 : NT - 1) * 64;  // tail: clamp DATA only;
    int c3 = (T + 3 < NT ? T + 3 : NT - 1) * 64;  // dest slots are never read
    TILE(0, c1, c2);
    TILE(1, c2, c3);
  }
#undef TILE
#undef VMC4
#undef BAR
#undef MFMA_Q
#undef RDB
#undef RDA
#undef STAGE_BH
#undef STAGE_AH
#undef STG_B
#undef STG_A

  asm volatile("s_waitcnt vmcnt(0)" ::: "memory");

  int rowb = m0 + wm * 64 + ((lane >> 4) << 2);
  int colb = n0 + wn * 32 + (lane & 15);
#pragma unroll
  for (int fn = 0; fn < 4; ++fn) {
    int n = colb + (fn >> 1) * 128 + (fn & 1) * 16;
    float bv = bias ? bias[n] : 0.f;
#pragma unroll
    for (int fm = 0; fm < 8; ++fm) {
      int mrow = rowb + (fm >> 2) * 128 + (fm & 3) * 16;
#pragma unroll
      for (int reg = 0; reg < 4; ++reg) {
        float v = acc[fm][fn][reg] * scale + bv;
        if (RELU) v = fmaxf(v, 0.f);
        int m = mrow + reg;
        if (OUTBF16) {
          bf16* C = (bf16*)Cv + (size_t)blockIdx.z * strideC;
          C[(size_t)m * N + n] = (bf16)v;
        } else {
          float* C = (float*)Cv + (size_t)blockIdx.z * strideC;
          C[(size_t)m * N + n] = v;
        }
      }
    }
  }
}

// ---------------------------------------------------------------------------
// smav: fused softmax + attn@V on MFMA.  R9: replaces the scalar softmax_av
// (128.6 us/dispatch, MfmaUtil 0, VALUBusy 34% -- latency-bound scalar AV).
// Block = 16 q-rows, 256 threads (4 waves).
//  Phase 1: wave w computes softmax rows w*4..w*4+3 in f32; stores the
//    UNNORMALIZED exp as bf16 into LDS P[16][2048] (XOR-swizzled: 16B granule
//    g at row r lives at g^(r&7)); row sum taken over the ROUNDED bf16 values
//    so the epilogue normalization is self-consistent.
//  Phase 2: wave w owns d-cols [w*16,w*16+16): 64x mfma_16x16x32 over K=2048;
//    A-frag = P (2-way LDS reads, free), B-frag = Vt[d][k] bf16 from L2.
//    Epilogue divides by rsum[row].
// LDS 64.06 KiB -> 2 blocks/CU. Grid (S/16, G).
// ---------------------------------------------------------------------------
__global__ __launch_bounds__(256) void smav(const float* __restrict__ adj,
                                            const bf16* __restrict__ Vt,
                                            float* __restrict__ out,
                                            long adjStride) {
  int z = blockIdx.y;
  const float* adjb = adj + (size_t)z * adjStride;
  const bf16* Vtb = Vt + (size_t)z * (D * S);
  float* outb = out + (size_t)z * (S * D);
  int q0 = blockIdx.x * 16;
  __shared__ __align__(16) bf16 P[16 * 2048];  // 64 KiB, swizzled
  __shared__ float rsum[16];
  int tid = threadIdx.x, w = tid >> 6, lane = tid & 63;
  char* Pc = (char*)&P[0];

  // ---- phase 1: softmax (rows w*4 .. w*4+3) ----
#pragma unroll
  for (int i = 0; i < 4; ++i) {
    int r = w * 4 + i;
    const float* rowp = adjb + (size_t)(q0 + r) * S + lane * 4;
    f32x4 rv[8];
    float lm = -1e30f;
#pragma unroll
    for (int kk = 0; kk < 8; ++kk) {
      rv[kk] = *(const f32x4*)(rowp + kk * 256);
      lm = fmaxf(lm, fmaxf(fmaxf(rv[kk].x, rv[kk].y), fmaxf(rv[kk].z, rv[kk].w)));
    }
#pragma unroll
    for (int off = 32; off > 0; off >>= 1) lm = fmaxf(lm, __shfl_xor(lm, off));
    float s = 0.f;
    uint32_t wbase = (uint32_t)(r * 4096 + (lane & 1) * 8);
#pragma unroll
    for (int kk = 0; kk < 8; ++kk) {
      bf16x4 pb;
      pb[0] = (bf16)__expf(rv[kk].x - lm);
      pb[1] = (bf16)__expf(rv[kk].y - lm);
      pb[2] = (bf16)__expf(rv[kk].z - lm);
      pb[3] = (bf16)__expf(rv[kk].w - lm);
      s += (float)pb[0] + (float)pb[1] + (float)pb[2] + (float)pb[3];
      uint32_t g = (uint32_t)(lane >> 1) + (uint32_t)(kk * 32);
      uint32_t gs = g ^ (uint32_t)(r & 7);  // low-3-bit XOR (granule swizzle)
      *(bf16x4*)(Pc + wbase + gs * 16) = pb;
    }
#pragma unroll
    for (int off = 32; off > 0; off >>= 1) s += __shfl_xor(s, off);
    if (lane == 0) rsum[r] = s;
  }
  __syncthreads();

  // ---- phase 2: out[q0..q0+16)[d0..d0+16) = P @ V^T-frag, MFMA ----
  int dl = (w << 4) + (lane & 15);
  const bf16* vrow = Vtb + (size_t)dl * S + (lane >> 4) * 8;
  uint32_t rl = (uint32_t)(lane & 15);
  uint32_t abase = rl * 4096;
  uint32_t rx = rl & 7;
  f32x4 acc0 = {0.f, 0.f, 0.f, 0.f}, acc1 = {0.f, 0.f, 0.f, 0.f};
#pragma unroll 4
  for (int k0 = 0; k0 < S; k0 += 64) {
    uint32_t g0 = (uint32_t)(k0 >> 3) + (uint32_t)(lane >> 4);
    bf16x8 a0 = *(const bf16x8*)(Pc + abase + ((g0 ^ rx) * 16));
    bf16x8 b0 = *(const bf16x8*)(vrow + k0);
    acc0 = __builtin_amdgcn_mfma_f32_16x16x32_bf16(a0, b0, acc0, 0, 0, 0);
    uint32_t g1 = g0 + 4;
    bf16x8 a1 = *(const bf16x8*)(Pc + abase + ((g1 ^ rx) * 16));
    bf16x8 b1 = *(const bf16x8*)(vrow + k0 + 32);
    acc1 = __builtin_amdgcn_mfma_f32_16x16x32_bf16(a1, b1, acc1, 0, 0, 0);
  }
  f32x4 accs = acc0 + acc1;
#pragma unroll
  for (int reg = 0; reg < 4; ++reg) {
    int m = ((lane >> 4) << 2) + reg;  // C/D layout: row=(lane>>4)*4+reg
    outb[(size_t)(q0 + m) * D + dl] = accs[reg] / rsum[m];
  }
}

// ---------------------------------------------------------------------------
extern "C" void kernel_launch(void* const* d_in, const int* in_sizes, int n_in,
                              void* d_out, int out_size, void* d_ws, size_t ws_size,
                              hipStream_t stream) {
  const float* Q  = (const float*)d_in[0];
  const float* Km = (const float*)d_in[1];
  const float* V  = (const float*)d_in[2];
  const float* W1 = (const float*)d_in[3];
  const float* b1 = (const float*)d_in[4];
  const float* W2 = (const float*)d_in[5];
  const float* b2 = (const float*)d_in[6];
  float* out = (float*)d_out;
  char* ws = (char*)d_ws;

  // layout: W1t 16M | W2t 16M | Qb16 2M | Kb16 2M | X (Sc bf16 / adj f32,
  // aliased) G*16M | h G*16M.  footprint = 36M + G*32M bytes.
  // Vt (bf16 [G][D][S], G*256KB) aliases the h region: written AFTER the
  // W2 gemm consumed h each group iteration, consumed by smav.
  bf16* W1t  = (bf16*)ws;
  bf16* W2t  = (bf16*)(ws + 16777216);
  bf16* Qb16 = (bf16*)(ws + 33554432);
  bf16* Kb16 = (bf16*)(ws + 35651584);

  transpose_cast<<<dim3(H / 64, S / 64), 256, 0, stream>>>(W1, W1t, S, H);
  transpose_cast<<<dim3(S / 64, H / 64), 256, 0, stream>>>(W2, W2t, H, S);
  cast_bf16<<<dim3(NB * S * D / 1024), 256, 0, stream>>>(Q, Qb16);
  cast_bf16<<<dim3(NB * S * D / 1024), 256, 0, stream>>>(Km, Kb16);

  int G = 1;
  if (ws_size >= 306184192ULL) G = 8;        // 292 MiB (R7 ran G=8 OK)
  else if (ws_size >= 171966464ULL) G = 4;
  else if (ws_size >= 104857600ULL) G = 2;

  bf16* Sc   = (bf16*)(ws + 37748736);
  float* adj = (float*)(ws + 37748736);
  bf16* h    = (bf16*)(ws + 37748736 + (size_t)G * 16777216);
  bf16* Vt   = h;  // alias, see layout note

  for (int b0 = 0; b0 < NB; b0 += G) {
    // scores = (Q @ K^T) / 8 via MFMA (K-dim = 64: keep the verified gemm_bt)
    gemm_bt<0, 1><<<dim3(S / 256, S / 128, G), 256, 0, stream>>>(
        Qb16 + (size_t)b0 * S * D, Kb16 + (size_t)b0 * S * D, nullptr, Sc,
        0.125f, S, S, D, (long)S * D, (long)S * D, (long)S * S);
    // big MLP GEMMs on the 8-phase 256^2 schedule
    gemm256<1, 1><<<dim3(H / 256, S / 256, G), 512, 0, stream>>>(
        Sc, W1t, b1, h, 1.0f, S, H, S, (long)S * S, 0L, (long)S * H);
    gemm256<0, 0><<<dim3(S / 256, S / 256, G), 512, 0, stream>>>(
        h, W2t, b2, adj, 1.0f, S, S, H, (long)S * H, 0L, (long)S * S);
    // V^T bf16 into the now-dead h region, then fused softmax + AV on MFMA
    vt_cast<<<dim3(S / 64, G), 256, 0, stream>>>(V + (size_t)b0 * S * D, Vt);
    smav<<<dim3(S / 16, G), 256, 0, stream>>>(
        adj, Vt, out + (size_t)b0 * S * D, (long)S * S);
  }
}

// Round 3
// 664.209 us; speedup vs baseline: 1.4144x; 1.0029x over previous
//
#include <hip/hip_runtime.h>
#include <hip/hip_bf16.h>
#include <stdint.h>

#define S 2048
#define D 64
#define H 4096
#define NB 8

typedef __bf16 bf16;
typedef __attribute__((ext_vector_type(8))) __bf16 bf16x8;
typedef __attribute__((ext_vector_type(4))) __bf16 bf16x4;
typedef __attribute__((ext_vector_type(4))) float f32x4;

// Raw LDS-DMA, invisible to the compiler's waitcnt pass (no auto vmcnt(0)).
// M0 = wave-uniform LDS byte offset; HW adds lane*16B. (R5-verified.)
__device__ __forceinline__ void dma16_raw(const bf16* g, uint32_t m0_bytes) {
  uint32_t m0s = __builtin_amdgcn_readfirstlane(m0_bytes);
  asm volatile("s_mov_b32 m0, %1\n\t"
               "global_load_lds_dwordx4 %0, off"
               :: "v"(g), "s"(m0s) : "memory");
}

__device__ __forceinline__ uint32_t lds_off_bytes(const void* p) {
  return (uint32_t)(uintptr_t)(__attribute__((address_space(3))) const void*)p;
}

// ---------------------------------------------------------------------------
// Transpose + cast: W [K][N] f32  ->  Wt [N][K] bf16   (weights, once per call)
// ---------------------------------------------------------------------------
__global__ __launch_bounds__(256) void transpose_cast(const float* __restrict__ W,
                                                      bf16* __restrict__ Wt,
                                                      int K, int N) {
  __shared__ float tile[64][65];
  int k0 = blockIdx.y * 64, n0 = blockIdx.x * 64;
  int c = threadIdx.x & 63;
  int r4 = threadIdx.x >> 6;
#pragma unroll
  for (int i = 0; i < 16; ++i) {
    int r = i * 4 + r4;
    tile[r][c] = W[(size_t)(k0 + r) * N + n0 + c];
  }
  __syncthreads();
#pragma unroll
  for (int i = 0; i < 16; ++i) {
    int r = i * 4 + r4;
    Wt[(size_t)(n0 + r) * K + k0 + c] = (bf16)tile[c][r];
  }
}

// ---------------------------------------------------------------------------
// Batched transpose + cast for V: V [z][S][D] f32 -> Vt [z][D][S] bf16.
// ---------------------------------------------------------------------------
__global__ __launch_bounds__(256) void vt_cast(const float* __restrict__ V,
                                               bf16* __restrict__ Vt) {
  __shared__ float tile[64][65];
  int z = blockIdx.y;
  int s0 = blockIdx.x * 64;
  const float* Vb = V + (size_t)z * (S * D);
  bf16* Vtb = Vt + (size_t)z * (D * S);
  int c = threadIdx.x & 63;
  int r4 = threadIdx.x >> 6;
#pragma unroll
  for (int i = 0; i < 16; ++i) {
    int r = i * 4 + r4;
    tile[r][c] = Vb[(size_t)(s0 + r) * D + c];
  }
  __syncthreads();
#pragma unroll
  for (int i = 0; i < 16; ++i) {
    int r = i * 4 + r4;  // r = d index
    Vtb[(size_t)r * S + s0 + c] = (bf16)tile[c][r];
  }
}

// ---------------------------------------------------------------------------
// Elementwise cast f32 -> bf16 (for Q, K). One float4 per thread.
// ---------------------------------------------------------------------------
__global__ __launch_bounds__(256) void cast_bf16(const float* __restrict__ x,
                                                 bf16* __restrict__ y) {
  int i = blockIdx.x * 256 + threadIdx.x;
  f32x4 v = ((const f32x4*)x)[i];
  bf16x4 o;
  o[0] = (bf16)v.x; o[1] = (bf16)v.y; o[2] = (bf16)v.z; o[3] = (bf16)v.w;
  ((bf16x4*)y)[i] = o;
}

// ---------------------------------------------------------------------------
// gemm_bt: kept (verified) for QK^T only (K=64 -> no deep pipeline to fill).
// ---------------------------------------------------------------------------
template <int RELU, int OUTBF16>
__global__ __launch_bounds__(256, 2) void gemm_bt(const bf16* __restrict__ A,
                                                  const bf16* __restrict__ Bt,
                                                  const float* __restrict__ bias,
                                                  void* __restrict__ Cv,
                                                  float scale,
                                                  int M, int N, int K,
                                                  long strideA, long strideB,
                                                  long strideC) {
  __shared__ __align__(16) bf16 smem[24576];
  int tid = threadIdx.x;
  int lane = tid & 63;
  int w = tid >> 6;

  int m0 = blockIdx.y * 128, n0 = blockIdx.x * 256;
  const bf16* Ab = A + (size_t)blockIdx.z * strideA;
  const bf16* Btb = Bt + (size_t)blockIdx.z * strideB;

  int grow = tid >> 2;
  int gcol = (((lane & 3) ^ ((lane >> 3) & 3)) * 8);
  const bf16* gA0 = Ab + (size_t)(m0 + grow) * K + gcol;
  const bf16* gA1 = gA0 + (size_t)64 * K;
  const bf16* gB0 = Btb + (size_t)(n0 + grow) * K + gcol;
  const bf16* gB1 = gB0 + (size_t)64 * K;
  const bf16* gB2 = gB0 + (size_t)128 * K;
  const bf16* gB3 = gB0 + (size_t)192 * K;

  uint32_t ldsBase = lds_off_bytes(&smem[0]);
  uint32_t wb = (uint32_t)(w * 1024);
  uint32_t mA[2], mB[2];
  mA[0] = ldsBase + wb;          mA[1] = ldsBase + 8192 + wb;
  mB[0] = ldsBase + 16384 + wb;  mB[1] = ldsBase + 32768 + wb;

  int mw = (w & 1) * 64, nw = (w >> 1) * 128;
  int lr = lane & 15;
  int ck = lane >> 4;
  int swz = (ck ^ ((lr >> 1) & 3)) * 8;
  const bf16* paBase = smem + (size_t)(mw + lr) * 32 + swz;
  const bf16* pbBase = smem + 8192 + (size_t)(nw + lr) * 32 + swz;

  f32x4 zero = {0.f, 0.f, 0.f, 0.f};
  f32x4 acc[4][8];
#pragma unroll
  for (int mt = 0; mt < 4; ++mt)
#pragma unroll
    for (int nt = 0; nt < 8; ++nt) acc[mt][nt] = zero;

  const int niter = K / 32;

#define STAGE(buf, koff)                                 \
  do {                                                   \
    dma16_raw(gA0 + (koff), mA[buf]);                    \
    dma16_raw(gA1 + (koff), mA[buf] + 4096);             \
    dma16_raw(gB0 + (koff), mB[buf]);                    \
    dma16_raw(gB1 + (koff), mB[buf] + 4096);             \
    dma16_raw(gB2 + (koff), mB[buf] + 8192);             \
    dma16_raw(gB3 + (koff), mB[buf] + 12288);            \
  } while (0)

  STAGE(0, 0);
  STAGE(1, 32);

  for (int it = 0; it < niter; ++it) {
    int buf = it & 1;
    asm volatile("s_waitcnt vmcnt(6)\n\ts_barrier" ::: "memory");
    const bf16* pa = paBase + buf * 4096;
    const bf16* pb = pbBase + buf * 8192;
    bf16x8 af[4], bfr[8];
#pragma unroll
    for (int mt = 0; mt < 4; ++mt) af[mt] = *(const bf16x8*)(pa + mt * (16 * 32));
#pragma unroll
    for (int nt = 0; nt < 8; ++nt) bfr[nt] = *(const bf16x8*)(pb + nt * (16 * 32));
    asm volatile("s_waitcnt lgkmcnt(0)\n\ts_barrier" ::: "memory");
    int kpre = it + 2 < niter ? (it + 2) * 32 : (niter - 1) * 32;
    STAGE(buf, kpre);
#pragma unroll
    for (int mt = 0; mt < 4; ++mt)
#pragma unroll
      for (int nt = 0; nt < 8; ++nt)
        acc[mt][nt] = __builtin_amdgcn_mfma_f32_16x16x32_bf16(af[mt], bfr[nt],
                                                              acc[mt][nt], 0, 0, 0);
  }
#undef STAGE
  asm volatile("s_waitcnt vmcnt(0)" ::: "memory");

  int mbase = m0 + mw + (lane >> 4) * 4;
  int nbase = n0 + nw + (lane & 15);
#pragma unroll
  for (int mt = 0; mt < 4; ++mt) {
#pragma unroll
    for (int nt = 0; nt < 8; ++nt) {
      int n = nbase + nt * 16;
      float bv = bias ? bias[n] : 0.f;
#pragma unroll
      for (int reg = 0; reg < 4; ++reg) {
        int m = mbase + mt * 16 + reg;
        float v = acc[mt][nt][reg] * scale + bv;
        if (RELU) v = fmaxf(v, 0.f);
        if (OUTBF16) {
          bf16* C = (bf16*)Cv + (size_t)blockIdx.z * strideC;
          C[(size_t)m * N + n] = (bf16)v;
        } else {
          float* C = (float*)Cv + (size_t)blockIdx.z * strideC;
          C[(size_t)m * N + n] = v;
        }
      }
    }
  }
}

// ---------------------------------------------------------------------------
// gemm256: 256x256 tile, BK=64, 512 threads (8 waves as 2Mx4N, 128x64/wave),
// 128 KiB LDS, counted-vmcnt quadrant schedule.
// R10: single barrier per quadrant-phase (4/tile, was 8). Old structure
// lockstepped [all-waves RD][all-waves MFMA] -> LDS and matrix pipe
// alternated idle (measured MfmaUtil 46% == serialized model). Now each
// MFMA cluster heads a section with the next phase's ds_reads/stages
// issued behind it: LDS drains inside MFMA windows (cross-wave skew +
// compiler interleave of independent-reg reads).
// Safety (counter-guaranteed, no latency margins):
//  - every region's ds_reads complete before that wave's first consuming
//    MFMA issues (compiler lgkmcnt), which precedes its next s_barrier;
//    every overwriting STAGE sits >=1 barrier later -> no WAR window.
//  - DMA issue order per tile (AH[PI^1,h1], BH[PI^1,h0], AH[PI,h0],
//    BH[PI,h1]) and the once-per-tile vmcnt(4) are identical to the
//    R8-verified schedule -> RAW invariant unchanged: at each tile
//    boundary exactly the two tile+2 halves may be outstanding.
// ---------------------------------------------------------------------------
template <int RELU, int OUTBF16>
__global__ __launch_bounds__(512, 2) void gemm256(const bf16* __restrict__ A,
                                                  const bf16* __restrict__ Bt,
                                                  const float* __restrict__ bias,
                                                  void* __restrict__ Cv,
                                                  float scale,
                                                  int M, int N, int K,
                                                  long strideA, long strideB,
                                                  long strideC) {
  __shared__ __align__(16) bf16 smem[65536];  // 128 KiB
  const char* smc = (const char*)&smem[0];

  int tid = threadIdx.x;
  int lane = tid & 63;
  int w = tid >> 6;
  int wm = w >> 2, wn = w & 3;  // 2M x 4N wave grid

  // bijective XCD swizzle (m204) over the x-y plane; z = batch untouched.
  unsigned gx = gridDim.x;
  unsigned nwg = gx * gridDim.y;
  unsigned flat = blockIdx.y * gx + blockIdx.x;
  unsigned q = nwg >> 3, r = nwg & 7, xcd = flat & 7, idx = flat >> 3;
  unsigned wg = (xcd < r ? xcd * (q + 1) : r * (q + 1) + (xcd - r) * q) + idx;
  int n0 = (int)(wg % gx) * 256;
  int m0 = (int)(wg / gx) * 256;

  const bf16* Ab = A + (size_t)blockIdx.z * strideA;
  const bf16* Btb = Bt + (size_t)blockIdx.z * strideB;

  // Staging: thread t covers LDS byte 16*t of each 8 KiB (64-row) load chunk:
  // row = t>>3, granule = t&7. Pre-swizzled global granule = (t&7)^(row&7).
  int trow = tid >> 3;
  int tg = (tid & 7) ^ (trow & 7);
  const bf16* pgA = Ab + (size_t)(m0 + trow) * K + tg * 8;
  const bf16* pgB = Btb + (size_t)(n0 + trow) * K + tg * 8;
  const size_t s64K = (size_t)K * 64;

  uint32_t ldsBase = lds_off_bytes(&smem[0]);
  uint32_t mb = ldsBase + (uint32_t)(w * 1024);  // wave-uniform DMA base

  // LDS read bases. A-frag (16x16x32): row=lane&15, k=(lane>>4)*8.
  int j = lane >> 4, b2 = (lane >> 2) & 1;
  uint32_t rbA0 = (uint32_t)(wm * 8192 + (lane & 15) * 128 +
                             ((j ^ (lane & 3)) * 16) + b2 * 64);
  uint32_t rbA1 = rbA0 ^ 64u;
  uint32_t rbB0 = (uint32_t)(65536 + wn * 4096 + (lane & 15) * 128 +
                             ((j ^ (lane & 3)) * 16) + b2 * 64);
  uint32_t rbB1 = rbB0 ^ 64u;

  f32x4 acc[8][4];  // [qa*4+mt][qb*2+nt]
#pragma unroll
  for (int a = 0; a < 8; ++a)
#pragma unroll
    for (int b = 0; b < 4; ++b) acc[a][b] = (f32x4){0.f, 0.f, 0.f, 0.f};

  bf16x8 af[4][2];   // current A quad [mt][kk]
  bf16x8 bf0[2][2];  // B quad 0 (held ph0 -> ph3, no re-read)
  bf16x8 bf1[2][2];  // B quad 1

#define STG_A(PI, HH, LL, KC) \
  dma16_raw(pgA + (size_t)(2 * (HH) + (LL)) * s64K + (KC), \
            mb + (PI) * 32768 + (HH) * 16384 + (LL) * 8192)
#define STG_B(PI, HH, LL, KC) \
  dma16_raw(pgB + (size_t)(2 * (HH) + (LL)) * s64K + (KC), \
            mb + 65536 + (PI) * 32768 + (HH) * 16384 + (LL) * 8192)
#define STAGE_AH(PI, HH, KC) do { STG_A(PI, HH, 0, KC); STG_A(PI, HH, 1, KC); } while (0)
#define STAGE_BH(PI, HH, KC) do { STG_B(PI, HH, 0, KC); STG_B(PI, HH, 1, KC); } while (0)

#define RDA(PI, QA)                                                            \
  do {                                                                        \
    _Pragma("unroll") for (int mt = 0; mt < 4; ++mt) {                        \
      af[mt][0] = *(const bf16x8*)(smc + rbA0 + ((PI) * 32768 + (QA) * 16384 + mt * 2048)); \
      af[mt][1] = *(const bf16x8*)(smc + rbA1 + ((PI) * 32768 + (QA) * 16384 + mt * 2048)); \
    }                                                                         \
  } while (0)
#define RDB(PI, QB, BF)                                                        \
  do {                                                                        \
    _Pragma("unroll") for (int nt = 0; nt < 2; ++nt) {                        \
      BF[nt][0] = *(const bf16x8*)(smc + rbB0 + ((PI) * 32768 + (QB) * 16384 + nt * 2048)); \
      BF[nt][1] = *(const bf16x8*)(smc + rbB1 + ((PI) * 32768 + (QB) * 16384 + nt * 2048)); \
    }                                                                         \
  } while (0)

#define MFMA_Q(QA, QB, BF)                                                     \
  do {                                                                        \
    __builtin_amdgcn_s_setprio(1);                                            \
    _Pragma("unroll") for (int mt = 0; mt < 4; ++mt)                          \
      _Pragma("unroll") for (int nt = 0; nt < 2; ++nt) {                      \
        f32x4 c = acc[(QA) * 4 + mt][(QB) * 2 + nt];                          \
        c = __builtin_amdgcn_mfma_f32_16x16x32_bf16(af[mt][0], BF[nt][0], c, 0, 0, 0); \
        c = __builtin_amdgcn_mfma_f32_16x16x32_bf16(af[mt][1], BF[nt][1], c, 0, 0, 0); \
        acc[(QA) * 4 + mt][(QB) * 2 + nt] = c;                                \
      }                                                                       \
    __builtin_amdgcn_s_setprio(0);                                            \
  } while (0)

#define BAR() asm volatile("s_barrier" ::: "memory")
#define VMC4() asm volatile("s_waitcnt vmcnt(4)" ::: "memory")

  // One K-tile, 4 barriers. MFMA clusters head sections; next-phase reads
  // and stages issue behind them (LDS drains under the MFMA window).
#define TILE(PI, KC1, KC2)            \
  do {                                \
    RDA(PI, 0);                       \
    RDB(PI, 0, bf0);                  \
    STAGE_AH((PI) ^ 1, 1, KC1);       \
    BAR();                            \
    MFMA_Q(0, 0, bf0);                \
    RDB(PI, 1, bf1);                  \
    STAGE_BH((PI) ^ 1, 0, KC1);       \
    BAR();                            \
    MFMA_Q(0, 1, bf1);                \
    RDA(PI, 1);                       \
    STAGE_AH(PI, 0, KC2);             \
    BAR();                            \
    MFMA_Q(1, 1, bf1);                \
    STAGE_BH(PI, 1, KC2);             \
    MFMA_Q(1, 0, bf0);                \
    VMC4();                           \
    BAR();                            \
  } while (0)

  // Prologue: issue halves in steady-state order so vmcnt(4) leaves exactly
  // the two tile-1 (ph2/ph3-slot) halves outstanding.
  STAGE_AH(0, 0, 0);
  STAGE_BH(0, 1, 0);
  STAGE_AH(0, 1, 0);
  STAGE_BH(0, 0, 0);
  STAGE_AH(1, 0, 64);
  STAGE_BH(1, 1, 64);
  asm volatile("s_waitcnt vmcnt(4)\n\ts_barrier" ::: "memory");

  const int NT = K / 64;  // even (K = 2048 or 4096)
  for (int T = 0; T < NT; T += 2) {
    int c1 = (T + 1) * 64;
    int c2 = (T + 2 < NT ? T + 2 : NT - 1) * 64;  // tail: clamp DATA only;
    int c3 = (T + 3 < NT ? T + 3 : NT - 1) * 64;  // dest slots are never read
    TILE(0, c1, c2);
    TILE(1, c2, c3);
  }
#undef TILE
#undef VMC4
#undef BAR
#undef MFMA_Q
#undef RDB
#undef RDA
#undef STAGE_BH
#undef STAGE_AH
#undef STG_B
#undef STG_A

  asm volatile("s_waitcnt vmcnt(0)" ::: "memory");

  int rowb = m0 + wm * 64 + ((lane >> 4) << 2);
  int colb = n0 + wn * 32 + (lane & 15);
#pragma unroll
  for (int fn = 0; fn < 4; ++fn) {
    int n = colb + (fn >> 1) * 128 + (fn & 1) * 16;
    float bv = bias ? bias[n] : 0.f;
#pragma unroll
    for (int fm = 0; fm < 8; ++fm) {
      int mrow = rowb + (fm >> 2) * 128 + (fm & 3) * 16;
#pragma unroll
      for (int reg = 0; reg < 4; ++reg) {
        float v = acc[fm][fn][reg] * scale + bv;
        if (RELU) v = fmaxf(v, 0.f);
        int m = mrow + reg;
        if (OUTBF16) {
          bf16* C = (bf16*)Cv + (size_t)blockIdx.z * strideC;
          C[(size_t)m * N + n] = (bf16)v;
        } else {
          float* C = (float*)Cv + (size_t)blockIdx.z * strideC;
          C[(size_t)m * N + n] = v;
        }
      }
    }
  }
}

// ---------------------------------------------------------------------------
// smav: fused softmax + attn@V on MFMA (R9; replaced 128us scalar AV).
// ---------------------------------------------------------------------------
__global__ __launch_bounds__(256) void smav(const float* __restrict__ adj,
                                            const bf16* __restrict__ Vt,
                                            float* __restrict__ out,
                                            long adjStride) {
  int z = blockIdx.y;
  const float* adjb = adj + (size_t)z * adjStride;
  const bf16* Vtb = Vt + (size_t)z * (D * S);
  float* outb = out + (size_t)z * (S * D);
  int q0 = blockIdx.x * 16;
  __shared__ __align__(16) bf16 P[16 * 2048];  // 64 KiB, swizzled
  __shared__ float rsum[16];
  int tid = threadIdx.x, w = tid >> 6, lane = tid & 63;
  char* Pc = (char*)&P[0];

  // ---- phase 1: softmax (rows w*4 .. w*4+3) ----
#pragma unroll
  for (int i = 0; i < 4; ++i) {
    int r = w * 4 + i;
    const float* rowp = adjb + (size_t)(q0 + r) * S + lane * 4;
    f32x4 rv[8];
    float lm = -1e30f;
#pragma unroll
    for (int kk = 0; kk < 8; ++kk) {
      rv[kk] = *(const f32x4*)(rowp + kk * 256);
      lm = fmaxf(lm, fmaxf(fmaxf(rv[kk].x, rv[kk].y), fmaxf(rv[kk].z, rv[kk].w)));
    }
#pragma unroll
    for (int off = 32; off > 0; off >>= 1) lm = fmaxf(lm, __shfl_xor(lm, off));
    float s = 0.f;
    uint32_t wbase = (uint32_t)(r * 4096 + (lane & 1) * 8);
#pragma unroll
    for (int kk = 0; kk < 8; ++kk) {
      bf16x4 pb;
      pb[0] = (bf16)__expf(rv[kk].x - lm);
      pb[1] = (bf16)__expf(rv[kk].y - lm);
      pb[2] = (bf16)__expf(rv[kk].z - lm);
      pb[3] = (bf16)__expf(rv[kk].w - lm);
      s += (float)pb[0] + (float)pb[1] + (float)pb[2] + (float)pb[3];
      uint32_t g = (uint32_t)(lane >> 1) + (uint32_t)(kk * 32);
      uint32_t gs = g ^ (uint32_t)(r & 7);  // low-3-bit XOR (granule swizzle)
      *(bf16x4*)(Pc + wbase + gs * 16) = pb;
    }
#pragma unroll
    for (int off = 32; off > 0; off >>= 1) s += __shfl_xor(s, off);
    if (lane == 0) rsum[r] = s;
  }
  __syncthreads();

  // ---- phase 2: out[q0..q0+16)[d0..d0+16) = P @ V^T-frag, MFMA ----
  int dl = (w << 4) + (lane & 15);
  const bf16* vrow = Vtb + (size_t)dl * S + (lane >> 4) * 8;
  uint32_t rl = (uint32_t)(lane & 15);
  uint32_t abase = rl * 4096;
  uint32_t rx = rl & 7;
  f32x4 acc0 = {0.f, 0.f, 0.f, 0.f}, acc1 = {0.f, 0.f, 0.f, 0.f};
#pragma unroll 4
  for (int k0 = 0; k0 < S; k0 += 64) {
    uint32_t g0 = (uint32_t)(k0 >> 3) + (uint32_t)(lane >> 4);
    bf16x8 a0 = *(const bf16x8*)(Pc + abase + ((g0 ^ rx) * 16));
    bf16x8 b0 = *(const bf16x8*)(vrow + k0);
    acc0 = __builtin_amdgcn_mfma_f32_16x16x32_bf16(a0, b0, acc0, 0, 0, 0);
    uint32_t g1 = g0 + 4;
    bf16x8 a1 = *(const bf16x8*)(Pc + abase + ((g1 ^ rx) * 16));
    bf16x8 b1 = *(const bf16x8*)(vrow + k0 + 32);
    acc1 = __builtin_amdgcn_mfma_f32_16x16x32_bf16(a1, b1, acc1, 0, 0, 0);
  }
  f32x4 accs = acc0 + acc1;
#pragma unroll
  for (int reg = 0; reg < 4; ++reg) {
    int m = ((lane >> 4) << 2) + reg;  // C/D layout: row=(lane>>4)*4+reg
    outb[(size_t)(q0 + m) * D + dl] = accs[reg] / rsum[m];
  }
}

// ---------------------------------------------------------------------------
extern "C" void kernel_launch(void* const* d_in, const int* in_sizes, int n_in,
                              void* d_out, int out_size, void* d_ws, size_t ws_size,
                              hipStream_t stream) {
  const float* Q  = (const float*)d_in[0];
  const float* Km = (const float*)d_in[1];
  const float* V  = (const float*)d_in[2];
  const float* W1 = (const float*)d_in[3];
  const float* b1 = (const float*)d_in[4];
  const float* W2 = (const float*)d_in[5];
  const float* b2 = (const float*)d_in[6];
  float* out = (float*)d_out;
  char* ws = (char*)d_ws;

  // layout: W1t 16M | W2t 16M | Qb16 2M | Kb16 2M | X (Sc bf16 / adj f32,
  // aliased) G*16M | h G*16M.  footprint = 36M + G*32M bytes.
  // Vt (bf16 [G][D][S], G*256KB) aliases the h region: written AFTER the
  // W2 gemm consumed h each group iteration, consumed by smav.
  bf16* W1t  = (bf16*)ws;
  bf16* W2t  = (bf16*)(ws + 16777216);
  bf16* Qb16 = (bf16*)(ws + 33554432);
  bf16* Kb16 = (bf16*)(ws + 35651584);

  transpose_cast<<<dim3(H / 64, S / 64), 256, 0, stream>>>(W1, W1t, S, H);
  transpose_cast<<<dim3(S / 64, H / 64), 256, 0, stream>>>(W2, W2t, H, S);
  cast_bf16<<<dim3(NB * S * D / 1024), 256, 0, stream>>>(Q, Qb16);
  cast_bf16<<<dim3(NB * S * D / 1024), 256, 0, stream>>>(Km, Kb16);

  int G = 1;
  if (ws_size >= 306184192ULL) G = 8;        // 292 MiB (R7 ran G=8 OK)
  else if (ws_size >= 171966464ULL) G = 4;
  else if (ws_size >= 104857600ULL) G = 2;

  bf16* Sc   = (bf16*)(ws + 37748736);
  float* adj = (float*)(ws + 37748736);
  bf16* h    = (bf16*)(ws + 37748736 + (size_t)G * 16777216);
  bf16* Vt   = h;  // alias, see layout note

  for (int b0 = 0; b0 < NB; b0 += G) {
    // scores = (Q @ K^T) / 8 via MFMA (K-dim = 64: keep the verified gemm_bt)
    gemm_bt<0, 1><<<dim3(S / 256, S / 128, G), 256, 0, stream>>>(
        Qb16 + (size_t)b0 * S * D, Kb16 + (size_t)b0 * S * D, nullptr, Sc,
        0.125f, S, S, D, (long)S * D, (long)S * D, (long)S * S);
    // big MLP GEMMs on the 4-barrier overlap schedule
    gemm256<1, 1><<<dim3(H / 256, S / 256, G), 512, 0, stream>>>(
        Sc, W1t, b1, h, 1.0f, S, H, S, (long)S * S, 0L, (long)S * H);
    gemm256<0, 0><<<dim3(S / 256, S / 256, G), 512, 0, stream>>>(
        h, W2t, b2, adj, 1.0f, S, S, H, (long)S * H, 0L, (long)S * S);
    // V^T bf16 into the now-dead h region, then fused softmax + AV on MFMA
    vt_cast<<<dim3(S / 64, G), 256, 0, stream>>>(V + (size_t)b0 * S * D, Vt);
    smav<<<dim3(S / 16, G), 256, 0, stream>>>(
        adj, Vt, out + (size_t)b0 * S * D, (long)S * S);
  }
}